// Round 1
// baseline (8367.505 us; speedup 1.0000x reference)
//
#include <hip/hip_runtime.h>
#include <stdint.h>

#define DEV static __device__ __forceinline__

using short8 = __attribute__((ext_vector_type(8))) short;
using f32x4  = __attribute__((ext_vector_type(4))) float;
using gbl_u32 = const __attribute__((address_space(1))) unsigned int;
using lds_u32 = __attribute__((address_space(3))) unsigned int;

DEV float bf2f(short s) {
  unsigned u = ((unsigned)(unsigned short)s) << 16;
  float f; __builtin_memcpy(&f, &u, 4); return f;
}
DEV short f2bf(float f) {
  unsigned u; __builtin_memcpy(&u, &f, 4);
  u = (u + 0x7fffu + ((u >> 16) & 1u)) >> 16;
  return (short)u;
}
DEV void gload_lds16(const void* g, void* l) {
  __builtin_amdgcn_global_load_lds((gbl_u32*)g, (lds_u32*)l, 16, 0, 0);
}
DEV float sigm(float x) { return 1.f / (1.f + __expf(-x)); }

// ------------------------------------------------------------------
// pack kernels (fp32 -> bf16, layout permutes)
// ------------------------------------------------------------------
__global__ void pack_cov_k(const float* __restrict__ past, const float* __restrict__ fut,
                           short* __restrict__ covp) {
  const int n = 192 * 256 * 64;
  for (int i = blockIdx.x * blockDim.x + threadIdx.x; i < n; i += gridDim.x * blockDim.x) {
    int c = i & 63, r = i >> 6;
    int b = r & 255, t = r >> 8;
    float v = (t < 128) ? past[((size_t)b * 128 + t) * 64 + c]
                        : fut[((size_t)b * 64 + (t - 128)) * 64 + c];
    covp[i] = f2bf(v);
  }
}

__global__ void pack_lab_k(const float* __restrict__ lab, short* __restrict__ labp) {
  const int n = 128 * 256 * 32;
  for (int i = blockIdx.x * blockDim.x + threadIdx.x; i < n; i += gridDim.x * blockDim.x) {
    int c = i & 31, r = i >> 5;
    int b = r & 255, t = r >> 8;
    labp[i] = f2bf(lab[((size_t)b * 128 + t) * 32 + c]);
  }
}

// packed row pr = j*96 + w  (j in [0,16), w in [0,96)): gate = w/32, u = w%32
// source row = gate*512 + j*32 + u   -> block j owns hidden units [32j, 32j+32)
DEV int gru_srcrow(int pr) {
  int j = pr / 96, w = pr % 96;
  return ((w >> 5) << 9) + j * 32 + (w & 31);
}

__global__ void pack_gru_k(const float* __restrict__ Wih, const float* __restrict__ Whh,
                           const float* __restrict__ bih, const float* __restrict__ bhh,
                           int Kin, short* __restrict__ Wihp, short* __restrict__ Whhp,
                           float* __restrict__ bihp, float* __restrict__ bhhp) {
  const int nW1 = 1536 * Kin, nW2 = 1536 * 512;
  const int total = nW1 + nW2 + 3072;
  for (int i = blockIdx.x * blockDim.x + threadIdx.x; i < total; i += gridDim.x * blockDim.x) {
    if (i < nW1) {
      int pr = i / Kin, k = i - pr * Kin;
      Wihp[i] = f2bf(Wih[(size_t)gru_srcrow(pr) * Kin + k]);
    } else if (i < nW1 + nW2) {
      int ii = i - nW1;
      int pr = ii >> 9, k = ii & 511;
      Whhp[ii] = f2bf(Whh[(size_t)gru_srcrow(pr) * 512 + k]);
    } else if (i < nW1 + nW2 + 1536) {
      int pr = i - nW1 - nW2;
      bihp[pr] = bih[gru_srcrow(pr)];
    } else {
      int pr = i - nW1 - nW2 - 1536;
      bhhp[pr] = bhh[gru_srcrow(pr)];
    }
  }
}

__global__ void pack_misc_k(const float* __restrict__ fw, const float* __restrict__ w1,
                            const float* __restrict__ w2, short* __restrict__ fwb,
                            short* __restrict__ w1b, short* __restrict__ w2b) {
  const int n1 = 64 * 512, n2 = 128 * 32, n3 = 128 * 128;
  const int total = n1 + n2 + n3;
  for (int i = blockIdx.x * blockDim.x + threadIdx.x; i < total; i += gridDim.x * blockDim.x) {
    if (i < n1) fwb[i] = f2bf(fw[i]);
    else if (i < n1 + n2) w1b[i - n1] = f2bf(w1[i - n1]);
    else w2b[i - n1 - n2] = f2bf(w2[i - n1 - n2]);
  }
}

// ------------------------------------------------------------------
// generic GEMM: C[M][N] = act(A[M][K](bf16) @ B[N][K](bf16)^T + bias[N])
// m97-style 128x128 tile, global_load_lds staging, 16x16x32 bf16 MFMA
// ------------------------------------------------------------------
template <int BK, bool OBF16, bool DOTANH>
__global__ __launch_bounds__(256) void gemm_bt_k(
    const short* __restrict__ A, const short* __restrict__ Bw,
    const float* __restrict__ bias, void* __restrict__ Cout,
    int M, int N, int K) {
  constexpr int BM = 128, BN = 128;
  __shared__ short As[BM * BK];
  __shared__ short Bs[BN * BK];
  const int tid = threadIdx.x, lane = tid & 63;
  const int wave = tid >> 6, wm = wave >> 1, wn = wave & 1;
  const int bm = blockIdx.x, bn = blockIdx.y;
  const int lm = lane & 15, lk = (lane >> 4) * 8;
  f32x4 acc[4][4] = {};
  for (int k0 = 0; k0 < K; k0 += BK) {
    constexpr int BYTES = BM * BK * 2;
#pragma unroll
    for (int it = 0; it < BYTES / 4096; ++it) {
      int o = it * 4096 + tid * 16;
      int row = o / (BK * 2);
      int col = o - row * (BK * 2);
      const char* srcA = (const char*)A + (((size_t)(bm * BM + row)) * K + k0) * 2 + col;
      gload_lds16(srcA, (char*)As + (o - lane * 16));
      int rb = bn * BN + row;
      if (rb >= N) rb = N - 1;
      const char* srcB = (const char*)Bw + (((size_t)rb) * K + k0) * 2 + col;
      gload_lds16(srcB, (char*)Bs + (o - lane * 16));
    }
    __syncthreads();
#pragma unroll
    for (int kk = 0; kk < BK / 32; ++kk) {
      short8 av[4], bv[4];
#pragma unroll
      for (int i = 0; i < 4; ++i)
        av[i] = *(const short8*)((const char*)As + ((wm * 64 + i * 16 + lm) * BK + kk * 32 + lk) * 2);
#pragma unroll
      for (int jv = 0; jv < 4; ++jv)
        bv[jv] = *(const short8*)((const char*)Bs + ((wn * 64 + jv * 16 + lm) * BK + kk * 32 + lk) * 2);
#pragma unroll
      for (int i = 0; i < 4; ++i)
#pragma unroll
        for (int jv = 0; jv < 4; ++jv)
          acc[i][jv] = __builtin_amdgcn_mfma_f32_16x16x32_bf16(av[i], bv[jv], acc[i][jv], 0, 0, 0);
    }
    __syncthreads();
  }
#pragma unroll
  for (int jv = 0; jv < 4; ++jv) {
    int col = bn * BN + wn * 64 + jv * 16 + lm;
    if (col >= N) continue;
    float bvl = bias[col];
#pragma unroll
    for (int i = 0; i < 4; ++i) {
      int row0 = bm * BM + wm * 64 + i * 16 + (lane >> 4) * 4;
#pragma unroll
      for (int r = 0; r < 4; ++r) {
        float v = acc[i][jv][r] + bvl;
        if (DOTANH) v = tanhf(v);
        size_t off = (size_t)(row0 + r) * N + col;
        if (OBF16) ((short*)Cout)[off] = f2bf(v);
        else ((float*)Cout)[off] = v;
      }
    }
  }
}

// ------------------------------------------------------------------
// GRU scan: persistent, 256 blocks = 16 batch-groups x 16 hidden-blocks.
// Block (g,j): batches [16g,16g+16), hidden [32j,32j+32) (rows j*96..j*96+96
// of the permuted Whh held in LDS). Per step: MFMA gh = h_{t-1} @ Whh_slice^T,
// gates, write h_t, then 16-block group barrier (device-scope counter).
// ------------------------------------------------------------------
__global__ __launch_bounds__(256) void gru_scan_k(
    const short* __restrict__ xg,    // [48*256*1536] bf16, permuted gate cols
    const short* __restrict__ Whhp,  // [1536*512] bf16 permuted rows
    const float* __restrict__ bhhp,  // [1536] permuted
    short* __restrict__ hbuf,        // [(192+1)*256*512] bf16, slot0 = zeros
    unsigned int* __restrict__ ctr,  // [16] zeroed before launch
    int t0) {
  __shared__ short Wl[96 * 512];
  __shared__ short hs[16 * 512];
  __shared__ float sc[2][16 * 100];
  __shared__ float bhs[96];
  const int tid = threadIdx.x, lane = tid & 63, wave = tid >> 6;
  const int g = blockIdx.x & 15, j = blockIdx.x >> 4;
  {
    const char* wsrc = (const char*)(Whhp + (size_t)j * 96 * 512);
#pragma unroll 4
    for (int it = 0; it < 24; ++it) {
      int o = it * 4096 + tid * 16;
      int row = o >> 10;
      gload_lds16(wsrc + (o ^ ((row & 7) << 4)), (char*)Wl + (o - lane * 16));
    }
    if (tid < 96) bhs[tid] = bhhp[j * 96 + tid];
  }
  const int wk = wave >> 1, wn3 = wave & 1;
  const int lm = lane & 15, lk = (lane >> 4) * 8;
  for (int tl = 0; tl < 48; ++tl) {
    const int t = t0 + tl;
    const char* hsrc = (const char*)(hbuf + ((size_t)t * 256 + g * 16) * 512);
#pragma unroll
    for (int it = 0; it < 4; ++it) {
      int o = it * 4096 + tid * 16;
      int row = o >> 10;
      gload_lds16(hsrc + (o ^ ((row & 7) << 4)), (char*)hs + (o - lane * 16));
    }
    __syncthreads();
    // prefetch xg (independent of h) -- overlaps the K-loop
    short xgv[2][3];
#pragma unroll
    for (int pp = 0; pp < 2; ++pp) {
      int p = pp * 256 + tid, m = p >> 5, u = p & 31;
      const short* xp = xg + ((size_t)tl * 256 + g * 16 + m) * 1536 + j * 96 + u;
      xgv[pp][0] = xp[0];
      xgv[pp][1] = xp[32];
      xgv[pp][2] = xp[64];
    }
    f32x4 a3[3] = {};
#pragma unroll
    for (int kq = 0; kq < 8; ++kq) {
      const int kb = ((wk * 8 + kq) * 32 + lk) * 2;
      int ha = (lm << 10) + kb;
      ha ^= (lm & 7) << 4;
      short8 av = *(const short8*)((const char*)hs + ha);
#pragma unroll
      for (int n = 0; n < 3; ++n) {
        int wr = (wn3 * 3 + n) * 16 + lm;
        int wa = (wr << 10) + kb;
        wa ^= (wr & 7) << 4;
        short8 bv = *(const short8*)((const char*)Wl + wa);
        a3[n] = __builtin_amdgcn_mfma_f32_16x16x32_bf16(av, bv, a3[n], 0, 0, 0);
      }
    }
#pragma unroll
    for (int n = 0; n < 3; ++n)
#pragma unroll
      for (int rr = 0; rr < 4; ++rr)
        sc[wk][((lane >> 4) * 4 + rr) * 100 + (wn3 * 3 + n) * 16 + lm] = a3[n][rr];
    __syncthreads();
#pragma unroll
    for (int pp = 0; pp < 2; ++pp) {
      int p = pp * 256 + tid, m = p >> 5, u = p & 31;
      float Sr = sc[0][m * 100 + u] + sc[1][m * 100 + u];
      float Sz = sc[0][m * 100 + 32 + u] + sc[1][m * 100 + 32 + u];
      float Sn = sc[0][m * 100 + 64 + u] + sc[1][m * 100 + 64 + u];
      int hpa = (m << 10) + (j * 32 + u) * 2;
      hpa ^= (m & 7) << 4;
      float hp = bf2f(*(const short*)((const char*)hs + hpa));
      float rg = sigm(bf2f(xgv[pp][0]) + Sr + bhs[u]);
      float zg = sigm(bf2f(xgv[pp][1]) + Sz + bhs[32 + u]);
      float ng = tanhf(bf2f(xgv[pp][2]) + rg * (Sn + bhs[64 + u]));
      float hn = (1.f - zg) * ng + zg * hp;
      hbuf[((size_t)(t + 1) * 256 + g * 16 + m) * 512 + j * 32 + u] = f2bf(hn);
    }
    __syncthreads();
    if (tid == 0) {
      __threadfence();
      atomicAdd(&ctr[g], 1u);
      const unsigned tgt = 16u * (tl + 1);
      while (__hip_atomic_load(&ctr[g], __ATOMIC_RELAXED, __HIP_MEMORY_SCOPE_AGENT) < tgt)
        __builtin_amdgcn_s_sleep(1);
      __threadfence();
    }
    __syncthreads();
  }
}

// ------------------------------------------------------------------
// VAE scan: one block per batch element, fully independent. Small weights
// transposed into LDS; D=64 state in registers of threads 0..63.
// ------------------------------------------------------------------
__global__ __launch_bounds__(128) void vae_k(
    const float* __restrict__ feat, const float* __restrict__ ctrlpre,
    const float* __restrict__ flow_u, const float* __restrict__ flow_w,
    const float* __restrict__ flow_b, const float* __restrict__ outW,
    const float* __restrict__ outb, const float* __restrict__ W1,
    const float* __restrict__ b1, const float* __restrict__ W2,
    const float* __restrict__ b2, const float* __restrict__ cmuW,
    const float* __restrict__ cmub, float* __restrict__ out) {
  __shared__ float outWt[64 * 32], cmuT[64 * 64], W1t[32 * 128], W2t[128 * 128];
  __shared__ float outb_s[32], b1_s[128], b2_s[128], cmub_s[64];
  __shared__ float mupr_s[64], preds_s[32], hdn_s[128], tmp_s[128];
  const int tid = threadIdx.x, b = blockIdx.x;
  for (int i = tid; i < 64 * 32; i += 128) { int k = i >> 5, o = i & 31; outWt[k * 32 + o] = outW[o * 64 + k]; }
  for (int i = tid; i < 64 * 64; i += 128) { int k = i >> 6, dd = i & 63; cmuT[k * 64 + dd] = cmuW[dd * 64 + k]; }
  for (int i = tid; i < 32 * 128; i += 128) { int k = i >> 7, c = i & 127; W1t[k * 128 + c] = W1[c * 32 + k]; }
  for (int i = tid; i < 128 * 128; i += 128) { int k = i >> 7, c = i & 127; W2t[k * 128 + c] = W2[c * 128 + k]; }
  if (tid < 32) outb_s[tid] = outb[tid];
  b1_s[tid] = b1[tid];
  b2_s[tid] = b2[tid];
  if (tid < 64) cmub_s[tid] = cmub[tid];
  float mu = 0.f, var = 1.f, fu = 0.f, fwv = 0.f, fbv = 0.f;
  if (tid < 64) { fu = flow_u[tid]; fwv = flow_w[tid]; fbv = flow_b[tid]; }
  __syncthreads();
  const int d = tid;
  for (int t = 0; t < 192; ++t) {
    size_t r = (size_t)t * 256 + b;
    float varpr = 0.f, muprv = 0.f;
    if (tid < 64) {
      float ft = feat[r * 64 + d];
      float a = tanhf(fwv * mu + fbv);
      muprv = fu * a + ft + mu;
      float coef = fu * fwv * (1.f - a * a);
      varpr = 2.f * coef * var + var + 1.f;
      mupr_s[d] = muprv;
    }
    __syncthreads();
    if (tid < 32) {
      float s = outb_s[tid];
#pragma unroll 8
      for (int k = 0; k < 64; ++k) s += mupr_s[k] * outWt[k * 32 + tid];
      preds_s[tid] = s;
      out[(size_t)b * 6144 + t * 32 + tid] = s;
    }
    __syncthreads();
    float cmraw = 0.f, cls = 0.f;
    if (t < 128) {
      if (tid < 64) {
        cmraw = ctrlpre[r * 128 + d];
        cls = ctrlpre[r * 128 + 64 + d];
      }
    } else {
      float h = b1_s[tid];
#pragma unroll 8
      for (int k = 0; k < 32; ++k) h += preds_s[k] * W1t[k * 128 + tid];
      hdn_s[tid] = tanhf(h);
      __syncthreads();
      float tv = b2_s[tid];
#pragma unroll 8
      for (int k = 0; k < 128; ++k) tv += hdn_s[k] * W2t[k * 128 + tid];
      tmp_s[tid] = tv;
      __syncthreads();
      if (tid < 64) { cmraw = tmp_s[d]; cls = tmp_s[64 + d]; }
    }
    if (tid < 64) {
      float mc = cmub_s[d];
#pragma unroll 8
      for (int k = 0; k < 64; ++k) mc += mupr_s[k] * cmuT[k * 64 + d];
      float cm = cmraw - mc;
      float cs = (cls > 20.f) ? cls : log1pf(__expf(cls));
      if (t >= 1) {
        out[1572864 + (size_t)b * 12224 + (size_t)(t - 1) * 64 + d] = cm;
        out[4702208 + (size_t)b * 12224 + (size_t)(t - 1) * 64 + d] = cs;
      }
      float s = cs + varpr;
      mu = (cs / s) * muprv + (varpr / s) * cm;
      var = varpr * cs / s;
    }
    __syncthreads();
  }
}

// ------------------------------------------------------------------
extern "C" void kernel_launch(void* const* d_in, const int* in_sizes, int n_in,
                              void* d_out, int out_size, void* d_ws, size_t ws_size,
                              hipStream_t stream) {
  (void)in_sizes; (void)n_in; (void)out_size; (void)ws_size;
  const float* past_input = (const float*)d_in[0];
  const float* past_label = (const float*)d_in[1];
  const float* future_input = (const float*)d_in[2];
  const float* Wih0 = (const float*)d_in[3];
  const float* Whh0 = (const float*)d_in[4];
  const float* bih0 = (const float*)d_in[5];
  const float* bhh0 = (const float*)d_in[6];
  const float* Wih1 = (const float*)d_in[7];
  const float* Whh1 = (const float*)d_in[8];
  const float* bih1 = (const float*)d_in[9];
  const float* bhh1 = (const float*)d_in[10];
  const float* flow_u = (const float*)d_in[11];
  const float* flow_w = (const float*)d_in[12];
  const float* flow_b = (const float*)d_in[13];
  const float* feat_W = (const float*)d_in[14];
  const float* feat_b = (const float*)d_in[15];
  const float* ctrl_W1 = (const float*)d_in[16];
  const float* ctrl_b1 = (const float*)d_in[17];
  const float* ctrl_W2 = (const float*)d_in[18];
  const float* ctrl_b2 = (const float*)d_in[19];
  const float* cmuW = (const float*)d_in[20];
  const float* cmub = (const float*)d_in[21];
  const float* outW = (const float*)d_in[22];
  const float* outb = (const float*)d_in[23];

  char* ws = (char*)d_ws;
  size_t off = 0;
  auto alloc = [&](size_t bytes) -> char* {
    char* p = ws + off;
    off += (bytes + 255) & ~(size_t)255;
    return p;
  };
  short* covp  = (short*)alloc(49152ull * 64 * 2);
  short* labp  = (short*)alloc(32768ull * 32 * 2);
  short* Wih0p = (short*)alloc(1536ull * 64 * 2);
  short* Whh0p = (short*)alloc(1536ull * 512 * 2);
  short* Wih1p = (short*)alloc(1536ull * 512 * 2);
  short* Whh1p = (short*)alloc(1536ull * 512 * 2);
  float* bih0p = (float*)alloc(1536 * 4);
  float* bhh0p = (float*)alloc(1536 * 4);
  float* bih1p = (float*)alloc(1536 * 4);
  float* bhh1p = (float*)alloc(1536 * 4);
  short* featWb = (short*)alloc(64ull * 512 * 2);
  short* W1b   = (short*)alloc(128ull * 32 * 2);
  short* W2b   = (short*)alloc(128ull * 128 * 2);
  short* xgc   = (short*)alloc(48ull * 256 * 1536 * 2);   // 37.75 MB, chunked
  short* h1buf = (short*)alloc(193ull * 256 * 512 * 2);
  short* cfbuf = (short*)alloc(193ull * 256 * 512 * 2);
  unsigned int* ctr = (unsigned int*)alloc(256);
  // after scans finish, overlay precompute buffers into the xg chunk region
  float* feat_all = (float*)xgc;                            // 12.58 MB
  short* hdnb     = (short*)((char*)xgc + 12582912);        //  8.39 MB
  float* ctrlpre  = (float*)((char*)xgc + 20971520);        // 16.78 MB

  hipMemsetAsync(h1buf, 0, 256 * 512 * 2, stream);  // h_{-1} = 0
  hipMemsetAsync(cfbuf, 0, 256 * 512 * 2, stream);

  pack_cov_k<<<2048, 256, 0, stream>>>(past_input, future_input, covp);
  pack_lab_k<<<1024, 256, 0, stream>>>(past_label, labp);
  pack_gru_k<<<1024, 256, 0, stream>>>(Wih0, Whh0, bih0, bhh0, 64, Wih0p, Whh0p, bih0p, bhh0p);
  pack_gru_k<<<1024, 256, 0, stream>>>(Wih1, Whh1, bih1, bhh1, 512, Wih1p, Whh1p, bih1p, bhh1p);
  pack_misc_k<<<64, 256, 0, stream>>>(feat_W, ctrl_W1, ctrl_W2, featWb, W1b, W2b);

  // layer 0: xg chunk GEMM + scan, 4 chunks of 48 steps
  for (int c = 0; c < 4; ++c) {
    gemm_bt_k<64, true, false><<<dim3(96, 12), 256, 0, stream>>>(
        covp + (size_t)c * 48 * 256 * 64, Wih0p, bih0p, xgc, 12288, 1536, 64);
    hipMemsetAsync(ctr, 0, 64, stream);
    gru_scan_k<<<256, 256, 0, stream>>>(xgc, Whh0p, bhh0p, h1buf, ctr, c * 48);
  }
  // layer 1
  for (int c = 0; c < 4; ++c) {
    gemm_bt_k<64, true, false><<<dim3(96, 12), 256, 0, stream>>>(
        h1buf + 256 * 512 + (size_t)c * 48 * 256 * 512, Wih1p, bih1p, xgc, 12288, 1536, 512);
    hipMemsetAsync(ctr, 0, 64, stream);
    gru_scan_k<<<256, 256, 0, stream>>>(xgc, Whh1p, bhh1p, cfbuf, ctr, c * 48);
  }
  // parallel precompute for the VAE scan
  gemm_bt_k<64, false, false><<<dim3(384, 1), 256, 0, stream>>>(
      cfbuf + 256 * 512, featWb, feat_b, feat_all, 49152, 64, 512);
  gemm_bt_k<32, true, true><<<dim3(256, 1), 256, 0, stream>>>(
      labp, W1b, ctrl_b1, hdnb, 32768, 128, 32);
  gemm_bt_k<64, false, false><<<dim3(256, 1), 256, 0, stream>>>(
      hdnb, W2b, ctrl_b2, ctrlpre, 32768, 128, 128);

  vae_k<<<256, 128, 0, stream>>>(feat_all, ctrlpre, flow_u, flow_w, flow_b,
                                 outW, outb, ctrl_W1, ctrl_b1, ctrl_W2, ctrl_b2,
                                 cmuW, cmub, (float*)d_out);
}

// Round 2
// 3955.374 us; speedup vs baseline: 2.1155x; 2.1155x over previous
//
#include <hip/hip_runtime.h>
#include <stdint.h>

#define DEV static __device__ __forceinline__

using short8 = __attribute__((ext_vector_type(8))) short;
using f32x4  = __attribute__((ext_vector_type(4))) float;
using gbl_u32 = const __attribute__((address_space(1))) unsigned int;
using lds_u32 = __attribute__((address_space(3))) unsigned int;

DEV float bf2f(short s) {
  unsigned u = ((unsigned)(unsigned short)s) << 16;
  float f; __builtin_memcpy(&f, &u, 4); return f;
}
DEV short f2bf(float f) {
  unsigned u; __builtin_memcpy(&u, &f, 4);
  u = (u + 0x7fffu + ((u >> 16) & 1u)) >> 16;
  return (short)u;
}
DEV void gload_lds16(const void* g, void* l) {
  __builtin_amdgcn_global_load_lds((gbl_u32*)g, (lds_u32*)l, 16, 0, 0);
}
DEV float sigm(float x) { return 1.f / (1.f + __expf(-x)); }

// ------------------------------------------------------------------
// pack kernels (fp32 -> bf16, layout permutes)
// ------------------------------------------------------------------
__global__ void pack_cov_k(const float* __restrict__ past, const float* __restrict__ fut,
                           short* __restrict__ covp) {
  const int n = 192 * 256 * 64;
  for (int i = blockIdx.x * blockDim.x + threadIdx.x; i < n; i += gridDim.x * blockDim.x) {
    int c = i & 63, r = i >> 6;
    int b = r & 255, t = r >> 8;
    float v = (t < 128) ? past[((size_t)b * 128 + t) * 64 + c]
                        : fut[((size_t)b * 64 + (t - 128)) * 64 + c];
    covp[i] = f2bf(v);
  }
}

__global__ void pack_lab_k(const float* __restrict__ lab, short* __restrict__ labp) {
  const int n = 128 * 256 * 32;
  for (int i = blockIdx.x * blockDim.x + threadIdx.x; i < n; i += gridDim.x * blockDim.x) {
    int c = i & 31, r = i >> 5;
    int b = r & 255, t = r >> 8;
    labp[i] = f2bf(lab[((size_t)b * 128 + t) * 32 + c]);
  }
}

// packed row pr = j*96 + w  (j in [0,16), w in [0,96)): gate = w/32, u = w%32
// source row = gate*512 + j*32 + u   -> block j owns hidden units [32j, 32j+32)
DEV int gru_srcrow(int pr) {
  int j = pr / 96, w = pr % 96;
  return ((w >> 5) << 9) + j * 32 + (w & 31);
}

__global__ void pack_gru_k(const float* __restrict__ Wih, const float* __restrict__ Whh,
                           const float* __restrict__ bih, const float* __restrict__ bhh,
                           int Kin, short* __restrict__ Wihp, short* __restrict__ Whhp,
                           float* __restrict__ bihp, float* __restrict__ bhhp) {
  const int nW1 = 1536 * Kin, nW2 = 1536 * 512;
  const int total = nW1 + nW2 + 3072;
  for (int i = blockIdx.x * blockDim.x + threadIdx.x; i < total; i += gridDim.x * blockDim.x) {
    if (i < nW1) {
      int pr = i / Kin, k = i - pr * Kin;
      Wihp[i] = f2bf(Wih[(size_t)gru_srcrow(pr) * Kin + k]);
    } else if (i < nW1 + nW2) {
      int ii = i - nW1;
      int pr = ii >> 9, k = ii & 511;
      Whhp[ii] = f2bf(Whh[(size_t)gru_srcrow(pr) * 512 + k]);
    } else if (i < nW1 + nW2 + 1536) {
      int pr = i - nW1 - nW2;
      bihp[pr] = bih[gru_srcrow(pr)];
    } else {
      int pr = i - nW1 - nW2 - 1536;
      bhhp[pr] = bhh[gru_srcrow(pr)];
    }
  }
}

__global__ void pack_misc_k(const float* __restrict__ fw, const float* __restrict__ w1,
                            const float* __restrict__ w2, short* __restrict__ fwb,
                            short* __restrict__ w1b, short* __restrict__ w2b) {
  const int n1 = 64 * 512, n2 = 128 * 32, n3 = 128 * 128;
  const int total = n1 + n2 + n3;
  for (int i = blockIdx.x * blockDim.x + threadIdx.x; i < total; i += gridDim.x * blockDim.x) {
    if (i < n1) fwb[i] = f2bf(fw[i]);
    else if (i < n1 + n2) w1b[i - n1] = f2bf(w1[i - n1]);
    else w2b[i - n1 - n2] = f2bf(w2[i - n1 - n2]);
  }
}

// ------------------------------------------------------------------
// generic GEMM: C[M][N] = act(A[M][K](bf16) @ B[N][K](bf16)^T + bias[N])
// ------------------------------------------------------------------
template <int BK, bool OBF16, bool DOTANH>
__global__ __launch_bounds__(256) void gemm_bt_k(
    const short* __restrict__ A, const short* __restrict__ Bw,
    const float* __restrict__ bias, void* __restrict__ Cout,
    int M, int N, int K) {
  constexpr int BM = 128, BN = 128;
  __shared__ short As[BM * BK];
  __shared__ short Bs[BN * BK];
  const int tid = threadIdx.x, lane = tid & 63;
  const int wave = tid >> 6, wm = wave >> 1, wn = wave & 1;
  const int bm = blockIdx.x, bn = blockIdx.y;
  const int lm = lane & 15, lk = (lane >> 4) * 8;
  f32x4 acc[4][4] = {};
  for (int k0 = 0; k0 < K; k0 += BK) {
    constexpr int BYTES = BM * BK * 2;
#pragma unroll
    for (int it = 0; it < BYTES / 4096; ++it) {
      int o = it * 4096 + tid * 16;
      int row = o / (BK * 2);
      int col = o - row * (BK * 2);
      const char* srcA = (const char*)A + (((size_t)(bm * BM + row)) * K + k0) * 2 + col;
      gload_lds16(srcA, (char*)As + (o - lane * 16));
      int rb = bn * BN + row;
      if (rb >= N) rb = N - 1;
      const char* srcB = (const char*)Bw + (((size_t)rb) * K + k0) * 2 + col;
      gload_lds16(srcB, (char*)Bs + (o - lane * 16));
    }
    __syncthreads();
#pragma unroll
    for (int kk = 0; kk < BK / 32; ++kk) {
      short8 av[4], bv[4];
#pragma unroll
      for (int i = 0; i < 4; ++i)
        av[i] = *(const short8*)((const char*)As + ((wm * 64 + i * 16 + lm) * BK + kk * 32 + lk) * 2);
#pragma unroll
      for (int jv = 0; jv < 4; ++jv)
        bv[jv] = *(const short8*)((const char*)Bs + ((wn * 64 + jv * 16 + lm) * BK + kk * 32 + lk) * 2);
#pragma unroll
      for (int i = 0; i < 4; ++i)
#pragma unroll
        for (int jv = 0; jv < 4; ++jv)
          acc[i][jv] = __builtin_amdgcn_mfma_f32_16x16x32_bf16(av[i], bv[jv], acc[i][jv], 0, 0, 0);
    }
    __syncthreads();
  }
#pragma unroll
  for (int jv = 0; jv < 4; ++jv) {
    int col = bn * BN + wn * 64 + jv * 16 + lm;
    if (col >= N) continue;
    float bvl = bias[col];
#pragma unroll
    for (int i = 0; i < 4; ++i) {
      int row0 = bm * BM + wm * 64 + i * 16 + (lane >> 4) * 4;
#pragma unroll
      for (int r = 0; r < 4; ++r) {
        float v = acc[i][jv][r] + bvl;
        if (DOTANH) v = tanhf(v);
        size_t off = (size_t)(row0 + r) * N + col;
        if (OBF16) ((short*)Cout)[off] = f2bf(v);
        else ((float*)Cout)[off] = v;
      }
    }
  }
}

// ------------------------------------------------------------------
// GRU scan: persistent, 256 blocks = 16 batch-groups x 16 hidden-blocks.
// COH=0: fence-based exchange (threadfence + global_load_lds)
// COH=1: agent-coherent atomic stores/loads for h, no cache-flush fences
// Counters padded to 256B/group; XCD-local group placement heuristic.
// ------------------------------------------------------------------
template <int COH>
__global__ __launch_bounds__(256) void gru_scan_k(
    const short* __restrict__ xg,    // [48*256*1536] bf16, permuted gate cols
    const short* __restrict__ Whhp,  // [1536*512] bf16 permuted rows
    const float* __restrict__ bhhp,  // [1536] permuted
    short* __restrict__ hbuf,        // [(192+1)*256*512] bf16, slot0 = zeros
    unsigned int* __restrict__ ctr,  // [16*64], zeroed once per launch
    int t0, unsigned int base) {
  __shared__ short Wl[96 * 512];
  __shared__ short hs[16 * 512];
  __shared__ float sc[2][16 * 101];
  __shared__ float bhs[96];
  const int tid = threadIdx.x, lane = tid & 63, wave = tid >> 6;
  const int x = blockIdx.x;
  const int g = (x & 7) + ((x >> 7) << 3);  // 16 blocks of group g share an XCD (%8 heuristic)
  const int j = (x >> 3) & 15;
  unsigned int* __restrict__ myctr = ctr + g * 64;
  unsigned int* __restrict__ hbuf32 = (unsigned int*)hbuf;
  {
    const char* wsrc = (const char*)(Whhp + (size_t)j * 96 * 512);
#pragma unroll 4
    for (int it = 0; it < 24; ++it) {
      int o = it * 4096 + tid * 16;
      int row = o >> 10;
      gload_lds16(wsrc + (o ^ ((row & 7) << 4)), (char*)Wl + (o - lane * 16));
    }
    if (tid < 96) bhs[tid] = bhhp[j * 96 + tid];
  }
  const int wk = wave >> 1, wn3 = wave & 1;
  const int lm = lane & 15, lk = (lane >> 4) * 8;
  const int m = tid >> 4, up = tid & 15, u0 = up * 2;
  for (int tl = 0; tl < 48; ++tl) {
    const int t = t0 + tl;
    // ---- stage h_t into LDS (swizzled rows of 1KB) ----
    if constexpr (COH == 0) {
      const char* hsrc = (const char*)(hbuf + ((size_t)t * 256 + g * 16) * 512);
#pragma unroll
      for (int it = 0; it < 4; ++it) {
        int o = it * 4096 + tid * 16;
        int row = o >> 10;
        gload_lds16(hsrc + (o ^ ((row & 7) << 4)), (char*)hs + (o - lane * 16));
      }
    } else {
      const unsigned int* hrow = hbuf32 + ((size_t)t * 256 + g * 16) * 256;
      unsigned int hv[16];
#pragma unroll
      for (int k = 0; k < 16; ++k)
        hv[k] = __hip_atomic_load(hrow + k * 256 + tid, __ATOMIC_RELAXED, __HIP_MEMORY_SCOPE_AGENT);
#pragma unroll
      for (int k = 0; k < 16; ++k) {
        int ba = ((k << 10) + tid * 4) ^ ((k & 7) << 4);
        *(unsigned int*)((char*)hs + ba) = hv[k];
      }
    }
    // xg loads (independent of h) -- consumed in the gate phase
    const unsigned int* xp = (const unsigned int*)(xg + ((size_t)tl * 256 + g * 16 + m) * 1536 + j * 96);
    unsigned int xr2 = xp[up], xz2 = xp[16 + up], xn2 = xp[32 + up];
    __syncthreads();
    // ---- gh = h_{t-1} @ Whh_slice^T ----
    f32x4 a3[3] = {};
#pragma unroll
    for (int kq = 0; kq < 8; ++kq) {
      const int kb = ((wk * 8 + kq) * 32 + lk) * 2;
      int ha = ((lm << 10) + kb) ^ ((lm & 7) << 4);
      short8 av = *(const short8*)((const char*)hs + ha);
#pragma unroll
      for (int n = 0; n < 3; ++n) {
        int wr = (wn3 * 3 + n) * 16 + lm;
        int wa = ((wr << 10) + kb) ^ ((wr & 7) << 4);
        short8 bv = *(const short8*)((const char*)Wl + wa);
        a3[n] = __builtin_amdgcn_mfma_f32_16x16x32_bf16(av, bv, a3[n], 0, 0, 0);
      }
    }
#pragma unroll
    for (int n = 0; n < 3; ++n)
#pragma unroll
      for (int rr = 0; rr < 4; ++rr)
        sc[wk][((lane >> 4) * 4 + rr) * 101 + (wn3 * 3 + n) * 16 + lm] = a3[n][rr];
    __syncthreads();
    // ---- gates (each thread: batch m, units u0,u0+1), packed u32 store ----
    {
      float Sr0 = sc[0][m * 101 + u0] + sc[1][m * 101 + u0];
      float Sr1 = sc[0][m * 101 + u0 + 1] + sc[1][m * 101 + u0 + 1];
      float Sz0 = sc[0][m * 101 + 32 + u0] + sc[1][m * 101 + 32 + u0];
      float Sz1 = sc[0][m * 101 + 33 + u0] + sc[1][m * 101 + 33 + u0];
      float Sn0 = sc[0][m * 101 + 64 + u0] + sc[1][m * 101 + 64 + u0];
      float Sn1 = sc[0][m * 101 + 65 + u0] + sc[1][m * 101 + 65 + u0];
      int hpa = ((m << 10) + (j * 32 + u0) * 2) ^ ((m & 7) << 4);
      unsigned int hpu = *(const unsigned int*)((const char*)hs + hpa);
      float hp0 = bf2f((short)(hpu & 0xffff)), hp1 = bf2f((short)(hpu >> 16));
      float r0 = sigm(bf2f((short)(xr2 & 0xffff)) + Sr0 + bhs[u0]);
      float r1 = sigm(bf2f((short)(xr2 >> 16)) + Sr1 + bhs[u0 + 1]);
      float z0 = sigm(bf2f((short)(xz2 & 0xffff)) + Sz0 + bhs[32 + u0]);
      float z1 = sigm(bf2f((short)(xz2 >> 16)) + Sz1 + bhs[33 + u0]);
      float n0 = tanhf(bf2f((short)(xn2 & 0xffff)) + r0 * (Sn0 + bhs[64 + u0]));
      float n1 = tanhf(bf2f((short)(xn2 >> 16)) + r1 * (Sn1 + bhs[65 + u0]));
      float h0 = (1.f - z0) * n0 + z0 * hp0;
      float h1 = (1.f - z1) * n1 + z1 * hp1;
      unsigned int hv = (unsigned int)(unsigned short)f2bf(h0) |
                        ((unsigned int)(unsigned short)f2bf(h1) << 16);
      size_t oi = ((size_t)(t + 1) * 256 + g * 16 + m) * 256 + j * 16 + up;
      if constexpr (COH)
        __hip_atomic_store(hbuf32 + oi, hv, __ATOMIC_RELAXED, __HIP_MEMORY_SCOPE_AGENT);
      else
        hbuf32[oi] = hv;
    }
    __syncthreads();
    // ---- 16-block group barrier (padded counter line) ----
    if (tid == 0) {
      if constexpr (COH == 0) {
        __threadfence();
        atomicAdd(myctr, 1u);
      } else {
        __hip_atomic_fetch_add(myctr, 1u, __ATOMIC_RELEASE, __HIP_MEMORY_SCOPE_AGENT);
      }
      const unsigned tgt = base + 16u * (tl + 1);
      while (__hip_atomic_load(myctr, __ATOMIC_RELAXED, __HIP_MEMORY_SCOPE_AGENT) < tgt)
        __builtin_amdgcn_s_sleep(1);
      if constexpr (COH == 0) __threadfence();
      __builtin_amdgcn_sched_barrier(0);
    }
    __syncthreads();
  }
}

// ------------------------------------------------------------------
// VAE scan: one block per batch element, fully independent.
// ------------------------------------------------------------------
__global__ __launch_bounds__(128) void vae_k(
    const float* __restrict__ feat, const float* __restrict__ ctrlpre,
    const float* __restrict__ flow_u, const float* __restrict__ flow_w,
    const float* __restrict__ flow_b, const float* __restrict__ outW,
    const float* __restrict__ outb, const float* __restrict__ W1,
    const float* __restrict__ b1, const float* __restrict__ W2,
    const float* __restrict__ b2, const float* __restrict__ cmuW,
    const float* __restrict__ cmub, float* __restrict__ out) {
  __shared__ float outWt[64 * 32], cmuT[64 * 64], W1t[32 * 128], W2t[128 * 128];
  __shared__ float outb_s[32], b1_s[128], b2_s[128], cmub_s[64];
  __shared__ float mupr_s[64], preds_s[32], hdn_s[128], tmp_s[128];
  const int tid = threadIdx.x, b = blockIdx.x;
  for (int i = tid; i < 64 * 32; i += 128) { int k = i >> 5, o = i & 31; outWt[k * 32 + o] = outW[o * 64 + k]; }
  for (int i = tid; i < 64 * 64; i += 128) { int k = i >> 6, dd = i & 63; cmuT[k * 64 + dd] = cmuW[dd * 64 + k]; }
  for (int i = tid; i < 32 * 128; i += 128) { int k = i >> 7, c = i & 127; W1t[k * 128 + c] = W1[c * 32 + k]; }
  for (int i = tid; i < 128 * 128; i += 128) { int k = i >> 7, c = i & 127; W2t[k * 128 + c] = W2[c * 128 + k]; }
  if (tid < 32) outb_s[tid] = outb[tid];
  b1_s[tid] = b1[tid];
  b2_s[tid] = b2[tid];
  if (tid < 64) cmub_s[tid] = cmub[tid];
  float mu = 0.f, var = 1.f, fu = 0.f, fwv = 0.f, fbv = 0.f;
  if (tid < 64) { fu = flow_u[tid]; fwv = flow_w[tid]; fbv = flow_b[tid]; }
  __syncthreads();
  const int d = tid;
  for (int t = 0; t < 192; ++t) {
    size_t r = (size_t)t * 256 + b;
    float varpr = 0.f, muprv = 0.f;
    if (tid < 64) {
      float ft = feat[r * 64 + d];
      float a = tanhf(fwv * mu + fbv);
      muprv = fu * a + ft + mu;
      float coef = fu * fwv * (1.f - a * a);
      varpr = 2.f * coef * var + var + 1.f;
      mupr_s[d] = muprv;
    }
    __syncthreads();
    if (tid < 32) {
      float s = outb_s[tid];
#pragma unroll 8
      for (int k = 0; k < 64; ++k) s += mupr_s[k] * outWt[k * 32 + tid];
      preds_s[tid] = s;
      out[(size_t)b * 6144 + t * 32 + tid] = s;
    }
    __syncthreads();
    float cmraw = 0.f, cls = 0.f;
    if (t < 128) {
      if (tid < 64) {
        cmraw = ctrlpre[r * 128 + d];
        cls = ctrlpre[r * 128 + 64 + d];
      }
    } else {
      float h = b1_s[tid];
#pragma unroll 8
      for (int k = 0; k < 32; ++k) h += preds_s[k] * W1t[k * 128 + tid];
      hdn_s[tid] = tanhf(h);
      __syncthreads();
      float tv = b2_s[tid];
#pragma unroll 8
      for (int k = 0; k < 128; ++k) tv += hdn_s[k] * W2t[k * 128 + tid];
      tmp_s[tid] = tv;
      __syncthreads();
      if (tid < 64) { cmraw = tmp_s[d]; cls = tmp_s[64 + d]; }
    }
    if (tid < 64) {
      float mc = cmub_s[d];
#pragma unroll 8
      for (int k = 0; k < 64; ++k) mc += mupr_s[k] * cmuT[k * 64 + d];
      float cm = cmraw - mc;
      float cs = (cls > 20.f) ? cls : log1pf(__expf(cls));
      if (t >= 1) {
        out[1572864 + (size_t)b * 12224 + (size_t)(t - 1) * 64 + d] = cm;
        out[4702208 + (size_t)b * 12224 + (size_t)(t - 1) * 64 + d] = cs;
      }
      float s = cs + varpr;
      mu = (cs / s) * muprv + (varpr / s) * cm;
      var = varpr * cs / s;
    }
    __syncthreads();
  }
}

// ------------------------------------------------------------------
extern "C" void kernel_launch(void* const* d_in, const int* in_sizes, int n_in,
                              void* d_out, int out_size, void* d_ws, size_t ws_size,
                              hipStream_t stream) {
  (void)in_sizes; (void)n_in; (void)out_size; (void)ws_size;
  const float* past_input = (const float*)d_in[0];
  const float* past_label = (const float*)d_in[1];
  const float* future_input = (const float*)d_in[2];
  const float* Wih0 = (const float*)d_in[3];
  const float* Whh0 = (const float*)d_in[4];
  const float* bih0 = (const float*)d_in[5];
  const float* bhh0 = (const float*)d_in[6];
  const float* Wih1 = (const float*)d_in[7];
  const float* Whh1 = (const float*)d_in[8];
  const float* bih1 = (const float*)d_in[9];
  const float* bhh1 = (const float*)d_in[10];
  const float* flow_u = (const float*)d_in[11];
  const float* flow_w = (const float*)d_in[12];
  const float* flow_b = (const float*)d_in[13];
  const float* feat_W = (const float*)d_in[14];
  const float* feat_b = (const float*)d_in[15];
  const float* ctrl_W1 = (const float*)d_in[16];
  const float* ctrl_b1 = (const float*)d_in[17];
  const float* ctrl_W2 = (const float*)d_in[18];
  const float* ctrl_b2 = (const float*)d_in[19];
  const float* cmuW = (const float*)d_in[20];
  const float* cmub = (const float*)d_in[21];
  const float* outW = (const float*)d_in[22];
  const float* outb = (const float*)d_in[23];

  char* ws = (char*)d_ws;
  size_t off = 0;
  auto alloc = [&](size_t bytes) -> char* {
    char* p = ws + off;
    off += (bytes + 255) & ~(size_t)255;
    return p;
  };
  short* covp  = (short*)alloc(49152ull * 64 * 2);
  short* labp  = (short*)alloc(32768ull * 32 * 2);
  short* Wih0p = (short*)alloc(1536ull * 64 * 2);
  short* Whh0p = (short*)alloc(1536ull * 512 * 2);
  short* Wih1p = (short*)alloc(1536ull * 512 * 2);
  short* Whh1p = (short*)alloc(1536ull * 512 * 2);
  float* bih0p = (float*)alloc(1536 * 4);
  float* bhh0p = (float*)alloc(1536 * 4);
  float* bih1p = (float*)alloc(1536 * 4);
  float* bhh1p = (float*)alloc(1536 * 4);
  short* featWb = (short*)alloc(64ull * 512 * 2);
  short* W1b   = (short*)alloc(128ull * 32 * 2);
  short* W2b   = (short*)alloc(128ull * 128 * 2);
  short* xgc   = (short*)alloc(48ull * 256 * 1536 * 2);   // 37.75 MB, chunked
  short* h1buf = (short*)alloc(193ull * 256 * 512 * 2);
  short* cfbuf = (short*)alloc(193ull * 256 * 512 * 2);
  unsigned int* ctr = (unsigned int*)alloc(16 * 256);     // 256B per group
  float* feat_all = (float*)xgc;                            // overlay after scans
  short* hdnb     = (short*)((char*)xgc + 12582912);
  float* ctrlpre  = (float*)((char*)xgc + 20971520);

  hipMemsetAsync(ctr, 0, 16 * 256, stream);
  hipMemsetAsync(h1buf, 0, 256 * 512 * 2, stream);  // h_{-1} = 0
  hipMemsetAsync(cfbuf, 0, 256 * 512 * 2, stream);

  pack_cov_k<<<2048, 256, 0, stream>>>(past_input, future_input, covp);
  pack_lab_k<<<1024, 256, 0, stream>>>(past_label, labp);
  pack_gru_k<<<1024, 256, 0, stream>>>(Wih0, Whh0, bih0, bhh0, 64, Wih0p, Whh0p, bih0p, bhh0p);
  pack_gru_k<<<1024, 256, 0, stream>>>(Wih1, Whh1, bih1, bhh1, 512, Wih1p, Whh1p, bih1p, bhh1p);
  pack_misc_k<<<64, 256, 0, stream>>>(feat_W, ctrl_W1, ctrl_W2, featWb, W1b, W2b);

  // layer 0: xg chunk GEMM + scan; A/B the barrier scheme across chunks
  for (int c = 0; c < 4; ++c) {
    gemm_bt_k<64, true, false><<<dim3(96, 12), 256, 0, stream>>>(
        covp + (size_t)c * 48 * 256 * 64, Wih0p, bih0p, xgc, 12288, 1536, 64);
    unsigned base = (unsigned)c * 768u;
    if (c & 1)
      gru_scan_k<1><<<256, 256, 0, stream>>>(xgc, Whh0p, bhh0p, h1buf, ctr, c * 48, base);
    else
      gru_scan_k<0><<<256, 256, 0, stream>>>(xgc, Whh0p, bhh0p, h1buf, ctr, c * 48, base);
  }
  // layer 1
  for (int c = 0; c < 4; ++c) {
    gemm_bt_k<64, true, false><<<dim3(96, 12), 256, 0, stream>>>(
        h1buf + 256 * 512 + (size_t)c * 48 * 256 * 512, Wih1p, bih1p, xgc, 12288, 1536, 512);
    unsigned base = (unsigned)(4 + c) * 768u;
    if (c & 1)
      gru_scan_k<1><<<256, 256, 0, stream>>>(xgc, Whh1p, bhh1p, cfbuf, ctr, c * 48, base);
    else
      gru_scan_k<0><<<256, 256, 0, stream>>>(xgc, Whh1p, bhh1p, cfbuf, ctr, c * 48, base);
  }
  // parallel precompute for the VAE scan
  gemm_bt_k<64, false, false><<<dim3(384, 1), 256, 0, stream>>>(
      cfbuf + 256 * 512, featWb, feat_b, feat_all, 49152, 64, 512);
  gemm_bt_k<32, true, true><<<dim3(256, 1), 256, 0, stream>>>(
      labp, W1b, ctrl_b1, hdnb, 32768, 128, 32);
  gemm_bt_k<64, false, false><<<dim3(256, 1), 256, 0, stream>>>(
      hdnb, W2b, ctrl_b2, ctrlpre, 32768, 128, 128);

  vae_k<<<256, 128, 0, stream>>>(feat_all, ctrlpre, flow_u, flow_w, flow_b,
                                 outW, outb, ctrl_W1, ctrl_b1, ctrl_W2, ctrl_b2,
                                 cmuW, cmub, (float*)d_out);
}

// Round 4
// 1755.048 us; speedup vs baseline: 4.7677x; 2.2537x over previous
//
#include <hip/hip_runtime.h>
#include <stdint.h>

#define DEV static __device__ __forceinline__

using short8 = __attribute__((ext_vector_type(8))) short;
using f32x4  = __attribute__((ext_vector_type(4))) float;
using gbl_u32 = const __attribute__((address_space(1))) unsigned int;
using lds_u32 = __attribute__((address_space(3))) unsigned int;

DEV float bf2f(short s) {
  unsigned u = ((unsigned)(unsigned short)s) << 16;
  float f; __builtin_memcpy(&f, &u, 4); return f;
}
DEV short f2bf(float f) {
  unsigned u; __builtin_memcpy(&u, &f, 4);
  u = (u + 0x7fffu + ((u >> 16) & 1u)) >> 16;
  return (short)u;
}
DEV void gload_lds16(const void* g, void* l) {
  __builtin_amdgcn_global_load_lds((gbl_u32*)g, (lds_u32*)l, 16, 0, 0);
}
DEV float sigm(float x) { return 1.f / (1.f + __expf(-x)); }

// ------------------------------------------------------------------
// pack kernels
// ------------------------------------------------------------------
__global__ void pack_cov_k(const float* __restrict__ past, const float* __restrict__ fut,
                           short* __restrict__ covp) {
  const int n = 192 * 256 * 64;
  for (int i = blockIdx.x * blockDim.x + threadIdx.x; i < n; i += gridDim.x * blockDim.x) {
    int c = i & 63, r = i >> 6;
    int b = r & 255, t = r >> 8;
    float v = (t < 128) ? past[((size_t)b * 128 + t) * 64 + c]
                        : fut[((size_t)b * 64 + (t - 128)) * 64 + c];
    covp[i] = f2bf(v);
  }
}

__global__ void pack_lab_k(const float* __restrict__ lab, short* __restrict__ labp) {
  const int n = 128 * 256 * 32;
  for (int i = blockIdx.x * blockDim.x + threadIdx.x; i < n; i += gridDim.x * blockDim.x) {
    int c = i & 31, r = i >> 5;
    int b = r & 255, t = r >> 8;
    labp[i] = f2bf(lab[((size_t)b * 128 + t) * 32 + c]);
  }
}

// Wih packed row pr = j*96 + w (w = gate*32 + u'): source row = gate*512 + j*32 + u'
DEV int gru_srcrow(int pr) {
  int j = pr / 96, w = pr % 96;
  return ((w >> 5) << 9) + j * 32 + (w & 31);
}

// Whh -> fragment image: [j(16)][kqg(16)*6+tile][lane(64)][8 elems]
// tile = wn3*3+n; packed-row w = tile*16 + (l&15); k = kqg*32 + (l>>4)*8 + i
__global__ void pack_gru_k(const float* __restrict__ Wih, const float* __restrict__ Whh,
                           const float* __restrict__ bih, const float* __restrict__ bhh,
                           int Kin, short* __restrict__ Wihp, short* __restrict__ Whhp,
                           float* __restrict__ bihp, float* __restrict__ bhhp) {
  const int nW1 = 1536 * Kin, nW2 = 1536 * 512;
  const int total = nW1 + nW2 + 3072;
  for (int idx = blockIdx.x * blockDim.x + threadIdx.x; idx < total; idx += gridDim.x * blockDim.x) {
    if (idx < nW1) {
      int pr = idx / Kin, k = idx - pr * Kin;
      Wihp[idx] = f2bf(Wih[(size_t)gru_srcrow(pr) * Kin + k]);
    } else if (idx < nW1 + nW2) {
      int ii = idx - nW1;
      int j = ii / 49152, r = ii - j * 49152;
      int i = r & 7, slot = r >> 3;
      int l = slot & 63, sf = slot >> 6;
      int kqg = sf / 6, tile = sf - kqg * 6;
      int w = tile * 16 + (l & 15);
      int k = kqg * 32 + (l >> 4) * 8 + i;
      int srow = (w >> 5) * 512 + j * 32 + (w & 31);
      Whhp[ii] = f2bf(Whh[(size_t)srow * 512 + k]);
    } else if (idx < nW1 + nW2 + 1536) {
      int pr = idx - nW1 - nW2;
      bihp[pr] = bih[gru_srcrow(pr)];
    } else {
      int pr = idx - nW1 - nW2 - 1536;
      bhhp[pr] = bhh[gru_srcrow(pr)];
    }
  }
}

__global__ void pack_misc_k(const float* __restrict__ fw, const float* __restrict__ w1,
                            const float* __restrict__ w2, short* __restrict__ fwb,
                            short* __restrict__ w1b, short* __restrict__ w2b) {
  const int n1 = 64 * 512, n2 = 128 * 32, n3 = 128 * 128;
  const int total = n1 + n2 + n3;
  for (int i = blockIdx.x * blockDim.x + threadIdx.x; i < total; i += gridDim.x * blockDim.x) {
    if (i < n1) fwb[i] = f2bf(fw[i]);
    else if (i < n1 + n2) w1b[i - n1] = f2bf(w1[i - n1]);
    else w2b[i - n1 - n2] = f2bf(w2[i - n1 - n2]);
  }
}

// ------------------------------------------------------------------
// GEMM: C[M][N] = act(A @ B^T + bias). AFRAG=true: A is in the hbuf
// fragment-image layout [t][g(16)][kqg(16)][lane(64)][8elems] (bf16).
// ------------------------------------------------------------------
template <int BK, bool OBF16, bool DOTANH, bool AFRAG>
__global__ __launch_bounds__(256) void gemm_bt_k(
    const short* __restrict__ A, const short* __restrict__ Bw,
    const float* __restrict__ bias, void* __restrict__ Cout,
    int M, int N, int K) {
  constexpr int BM = 128, BN = 128;
  __shared__ short As[BM * BK];
  __shared__ short Bs[BN * BK];
  const int tid = threadIdx.x, lane = tid & 63;
  const int wave = tid >> 6, wm = wave >> 1, wn = wave & 1;
  const int bm = blockIdx.x, bn = blockIdx.y;
  const int lm = lane & 15, lk = (lane >> 4) * 8;
  f32x4 acc[4][4] = {};
  for (int k0 = 0; k0 < K; k0 += BK) {
    constexpr int BYTES = BM * BK * 2;
#pragma unroll
    for (int it = 0; it < BYTES / 4096; ++it) {
      int o = it * 4096 + tid * 16;
      if (AFRAG) {
        int sub = o >> 10, gl = sub >> 1, kk2 = sub & 1, inb = o & 1023;
        size_t region = ((size_t)(bm >> 1) * 16 + (bm & 1) * 8 + gl) * 16 + (k0 >> 5) + kk2;
        gload_lds16((const char*)A + region * 1024 + inb, (char*)As + (o - lane * 16));
      } else {
        int row = o / (BK * 2);
        int col = o - row * (BK * 2);
        const char* srcA = (const char*)A + (((size_t)(bm * BM + row)) * K + k0) * 2 + col;
        gload_lds16(srcA, (char*)As + (o - lane * 16));
      }
      int row = o / (BK * 2);
      int col = o - row * (BK * 2);
      int rb = bn * BN + row;
      if (rb >= N) rb = N - 1;
      const char* srcB = (const char*)Bw + (((size_t)rb) * K + k0) * 2 + col;
      gload_lds16(srcB, (char*)Bs + (o - lane * 16));
    }
    __syncthreads();
#pragma unroll
    for (int kk = 0; kk < BK / 32; ++kk) {
      short8 av[4], bv[4];
#pragma unroll
      for (int i = 0; i < 4; ++i) {
        if (AFRAG)
          av[i] = *(const short8*)((const char*)As + (((wm * 4 + i) * 2 + kk) << 10) + lane * 16);
        else
          av[i] = *(const short8*)((const char*)As + ((wm * 64 + i * 16 + lm) * BK + kk * 32 + lk) * 2);
      }
#pragma unroll
      for (int jv = 0; jv < 4; ++jv)
        bv[jv] = *(const short8*)((const char*)Bs + ((wn * 64 + jv * 16 + lm) * BK + kk * 32 + lk) * 2);
#pragma unroll
      for (int i = 0; i < 4; ++i)
#pragma unroll
        for (int jv = 0; jv < 4; ++jv)
          acc[i][jv] = __builtin_amdgcn_mfma_f32_16x16x32_bf16(av[i], bv[jv], acc[i][jv], 0, 0, 0);
    }
    __syncthreads();
  }
#pragma unroll
  for (int jv = 0; jv < 4; ++jv) {
    int col = bn * BN + wn * 64 + jv * 16 + lm;
    if (col >= N) continue;
    float bvl = bias[col];
#pragma unroll
    for (int i = 0; i < 4; ++i) {
      int row0 = bm * BM + wm * 64 + i * 16 + (lane >> 4) * 4;
#pragma unroll
      for (int r = 0; r < 4; ++r) {
        float v = acc[i][jv][r] + bvl;
        if (DOTANH) v = tanhf(v);
        size_t off = (size_t)(row0 + r) * N + col;
        if (OBF16) ((short*)Cout)[off] = f2bf(v);
        else ((float*)Cout)[off] = v;
      }
    }
  }
}

// ------------------------------------------------------------------
// GRU scan. 256 blocks = 16 batch-groups x 16 hidden-blocks.
// h exchange: sc1 write-through stores (agent relaxed atomics); readers use
// fresh addresses; ordering from __syncthreads vmcnt-drain. No fences.
// Per-dispatch counter/flag segments, base 0 (R3 deadlock was cross-dispatch
// base accounting). Spins bounded: a sync bug -> wrong answer, not a hang.
// SCHEME 1: relaxed counter RMW + tid0 poll. SCHEME 2: flag array, 16-lane poll.
// hbuf fragment image: [t][g][kqg=j][lhi(4)][b(16)][i(8)] bf16.
// ------------------------------------------------------------------
template <int SCHEME>
__global__ __launch_bounds__(256) void gru_scan_k(
    const short* __restrict__ xg,     // [48*256*1536] bf16, w-permuted cols
    const short* __restrict__ Whhp,   // fragment image, 96KB per j
    const float* __restrict__ bhhp,   // [1536] w-permuted
    short* __restrict__ hbuf,         // [(192+1)][16g][8192] bf16, slot0 zeros
    unsigned int* __restrict__ ctr,   // this dispatch's [16 groups * 64] segment
    unsigned int* __restrict__ flags, // this dispatch's [16 groups * 16] segment
    int t0) {
  __shared__ short Wl[96 * 512];
  __shared__ short hs[16 * 512];
  __shared__ float sc[2][16 * 101];
  __shared__ float bhs[96];
  const int tid = threadIdx.x, lane = tid & 63, wave = tid >> 6;
  const int x = blockIdx.x;
  const int g = (x & 7) + ((x >> 7) << 3);  // group XCD-local (perf heuristic only)
  const int j = (x >> 3) & 15;
  unsigned int* __restrict__ myctr = ctr + g * 64;
  unsigned int* __restrict__ myflags = flags + g * 16;
  unsigned int* __restrict__ hbuf32 = (unsigned int*)hbuf;
  {
    const char* wsrc = (const char*)Whhp + (size_t)j * 98304;
#pragma unroll 4
    for (int it = 0; it < 24; ++it) {
      int o = it * 4096 + tid * 16;
      gload_lds16(wsrc + o, (char*)Wl + (o - lane * 16));
    }
    if (tid < 96) bhs[tid] = bhhp[j * 96 + tid];
  }
  const int wk = wave >> 1, wn3 = wave & 1;
  const int m = tid >> 4, up = tid & 15, u0 = up * 2;
  for (int tl = 0; tl < 48; ++tl) {
    const int t = t0 + tl;
    // ---- stage full h_t (16KB, linear fragment image) ----
    const char* hsrc = (const char*)hbuf + ((size_t)t * 16 + g) * 16384;
#pragma unroll
    for (int it = 0; it < 4; ++it) {
      int o = it * 4096 + tid * 16;
      gload_lds16(hsrc + o, (char*)hs + (o - lane * 16));
    }
    // xg loads (independent of h), consumed in gate phase
    const unsigned int* xp = (const unsigned int*)(xg + ((size_t)tl * 256 + g * 16 + m) * 1536 + j * 96);
    unsigned int xr2 = xp[up], xz2 = xp[16 + up], xn2 = xp[32 + up];
    __syncthreads();
    // ---- gh = h @ Whh_slice^T : all LDS reads are base + lane*16 ----
    f32x4 a3[3] = {};
#pragma unroll
    for (int kq = 0; kq < 8; ++kq) {
      int kqg = wk * 8 + kq;
      short8 av = *(const short8*)((const char*)hs + (kqg << 10) + lane * 16);
#pragma unroll
      for (int n = 0; n < 3; ++n) {
        short8 bv = *(const short8*)((const char*)Wl + ((kqg * 6 + wn3 * 3 + n) << 10) + lane * 16);
        a3[n] = __builtin_amdgcn_mfma_f32_16x16x32_bf16(av, bv, a3[n], 0, 0, 0);
      }
    }
#pragma unroll
    for (int n = 0; n < 3; ++n)
#pragma unroll
      for (int rr = 0; rr < 4; ++rr)
        sc[wk][((lane >> 4) * 4 + rr) * 101 + (wn3 * 3 + n) * 16 + (lane & 15)] = a3[n][rr];
    __syncthreads();
    // ---- gates: thread = (batch m, units u0,u0+1); sc1 write-through store ----
    {
      float Sr0 = sc[0][m * 101 + u0] + sc[1][m * 101 + u0];
      float Sr1 = sc[0][m * 101 + u0 + 1] + sc[1][m * 101 + u0 + 1];
      float Sz0 = sc[0][m * 101 + 32 + u0] + sc[1][m * 101 + 32 + u0];
      float Sz1 = sc[0][m * 101 + 33 + u0] + sc[1][m * 101 + 33 + u0];
      float Sn0 = sc[0][m * 101 + 64 + u0] + sc[1][m * 101 + 64 + u0];
      float Sn1 = sc[0][m * 101 + 65 + u0] + sc[1][m * 101 + 65 + u0];
      int hpa = ((j * 64 + (up >> 2) * 16 + m) << 4) + ((u0 & 7) << 1);
      unsigned int hpu = *(const unsigned int*)((const char*)hs + hpa);
      float hp0 = bf2f((short)(hpu & 0xffff)), hp1 = bf2f((short)(hpu >> 16));
      float r0 = sigm(bf2f((short)(xr2 & 0xffff)) + Sr0 + bhs[u0]);
      float r1 = sigm(bf2f((short)(xr2 >> 16)) + Sr1 + bhs[u0 + 1]);
      float z0 = sigm(bf2f((short)(xz2 & 0xffff)) + Sz0 + bhs[32 + u0]);
      float z1 = sigm(bf2f((short)(xz2 >> 16)) + Sz1 + bhs[33 + u0]);
      float n0 = tanhf(bf2f((short)(xn2 & 0xffff)) + r0 * (Sn0 + bhs[64 + u0]));
      float n1 = tanhf(bf2f((short)(xn2 >> 16)) + r1 * (Sn1 + bhs[65 + u0]));
      float h0 = (1.f - z0) * n0 + z0 * hp0;
      float h1 = (1.f - z1) * n1 + z1 * hp1;
      unsigned int hv = (unsigned int)(unsigned short)f2bf(h0) |
                        ((unsigned int)(unsigned short)f2bf(h1) << 16);
      size_t oi = ((size_t)(t + 1) * 16 + g) * 4096 +
                  (j * 64 + (up >> 2) * 16 + m) * 4 + (up & 3);
      __hip_atomic_store(hbuf32 + oi, hv, __ATOMIC_RELAXED, __HIP_MEMORY_SCOPE_AGENT);
    }
    __syncthreads();  // drains all lanes' vmcnt -> stores acked at coherence point
    // ---- 16-block group barrier (bounded spin) ----
    if constexpr (SCHEME == 1) {
      if (tid == 0) {
        __hip_atomic_fetch_add(myctr, 1u, __ATOMIC_RELAXED, __HIP_MEMORY_SCOPE_AGENT);
        const unsigned tgt = 16u * (unsigned)(tl + 1);
        int guard = 0;
        while (__hip_atomic_load(myctr, __ATOMIC_RELAXED, __HIP_MEMORY_SCOPE_AGENT) < tgt &&
               ++guard < 200000) {}
      }
    } else {
      const unsigned tgt = (unsigned)(tl + 1);
      if (tid == 0)
        __hip_atomic_store(myflags + j, tgt, __ATOMIC_RELAXED, __HIP_MEMORY_SCOPE_AGENT);
      if (tid < 16) {
        int guard = 0;
        while (__hip_atomic_load(myflags + tid, __ATOMIC_RELAXED, __HIP_MEMORY_SCOPE_AGENT) < tgt &&
               ++guard < 200000) {}
      }
    }
    __syncthreads();
  }
}

// ------------------------------------------------------------------
// VAE scan: one block per batch element.
// ------------------------------------------------------------------
__global__ __launch_bounds__(128) void vae_k(
    const float* __restrict__ feat, const float* __restrict__ ctrlpre,
    const float* __restrict__ flow_u, const float* __restrict__ flow_w,
    const float* __restrict__ flow_b, const float* __restrict__ outW,
    const float* __restrict__ outb, const float* __restrict__ W1,
    const float* __restrict__ b1, const float* __restrict__ W2,
    const float* __restrict__ b2, const float* __restrict__ cmuW,
    const float* __restrict__ cmub, float* __restrict__ out) {
  __shared__ float outWt[64 * 32], cmuT[64 * 64], W1t[32 * 128], W2t[128 * 128];
  __shared__ float outb_s[32], b1_s[128], b2_s[128], cmub_s[64];
  __shared__ float mupr_s[64], preds_s[32], hdn_s[128], tmp_s[128];
  const int tid = threadIdx.x, b = blockIdx.x;
  for (int i = tid; i < 64 * 32; i += 128) { int k = i >> 5, o = i & 31; outWt[k * 32 + o] = outW[o * 64 + k]; }
  for (int i = tid; i < 64 * 64; i += 128) { int k = i >> 6, dd = i & 63; cmuT[k * 64 + dd] = cmuW[dd * 64 + k]; }
  for (int i = tid; i < 32 * 128; i += 128) { int k = i >> 7, c = i & 127; W1t[k * 128 + c] = W1[c * 32 + k]; }
  for (int i = tid; i < 128 * 128; i += 128) { int k = i >> 7, c = i & 127; W2t[k * 128 + c] = W2[c * 128 + k]; }
  if (tid < 32) outb_s[tid] = outb[tid];
  b1_s[tid] = b1[tid];
  b2_s[tid] = b2[tid];
  if (tid < 64) cmub_s[tid] = cmub[tid];
  float mu = 0.f, var = 1.f, fu = 0.f, fwv = 0.f, fbv = 0.f;
  if (tid < 64) { fu = flow_u[tid]; fwv = flow_w[tid]; fbv = flow_b[tid]; }
  __syncthreads();
  const int d = tid;
  for (int t = 0; t < 192; ++t) {
    size_t r = (size_t)t * 256 + b;
    float varpr = 0.f, muprv = 0.f;
    if (tid < 64) {
      float ft = feat[r * 64 + d];
      float a = tanhf(fwv * mu + fbv);
      muprv = fu * a + ft + mu;
      float coef = fu * fwv * (1.f - a * a);
      varpr = 2.f * coef * var + var + 1.f;
      mupr_s[d] = muprv;
    }
    __syncthreads();
    if (tid < 32) {
      float s = outb_s[tid];
#pragma unroll 8
      for (int k = 0; k < 64; ++k) s += mupr_s[k] * outWt[k * 32 + tid];
      preds_s[tid] = s;
      out[(size_t)b * 6144 + t * 32 + tid] = s;
    }
    __syncthreads();
    float cmraw = 0.f, cls = 0.f;
    if (t < 128) {
      if (tid < 64) {
        cmraw = ctrlpre[r * 128 + d];
        cls = ctrlpre[r * 128 + 64 + d];
      }
    } else {
      float h = b1_s[tid];
#pragma unroll 8
      for (int k = 0; k < 32; ++k) h += preds_s[k] * W1t[k * 128 + tid];
      hdn_s[tid] = tanhf(h);
      __syncthreads();
      float tv = b2_s[tid];
#pragma unroll 8
      for (int k = 0; k < 128; ++k) tv += hdn_s[k] * W2t[k * 128 + tid];
      tmp_s[tid] = tv;
      __syncthreads();
      if (tid < 64) { cmraw = tmp_s[d]; cls = tmp_s[64 + d]; }
    }
    if (tid < 64) {
      float mc = cmub_s[d];
#pragma unroll 8
      for (int k = 0; k < 64; ++k) mc += mupr_s[k] * cmuT[k * 64 + d];
      float cm = cmraw - mc;
      float cs = (cls > 20.f) ? cls : log1pf(__expf(cls));
      if (t >= 1) {
        out[1572864 + (size_t)b * 12224 + (size_t)(t - 1) * 64 + d] = cm;
        out[4702208 + (size_t)b * 12224 + (size_t)(t - 1) * 64 + d] = cs;
      }
      float s = cs + varpr;
      mu = (cs / s) * muprv + (varpr / s) * cm;
      var = varpr * cs / s;
    }
    __syncthreads();
  }
}

// ------------------------------------------------------------------
extern "C" void kernel_launch(void* const* d_in, const int* in_sizes, int n_in,
                              void* d_out, int out_size, void* d_ws, size_t ws_size,
                              hipStream_t stream) {
  (void)in_sizes; (void)n_in; (void)out_size; (void)ws_size;
  const float* past_input = (const float*)d_in[0];
  const float* past_label = (const float*)d_in[1];
  const float* future_input = (const float*)d_in[2];
  const float* Wih0 = (const float*)d_in[3];
  const float* Whh0 = (const float*)d_in[4];
  const float* bih0 = (const float*)d_in[5];
  const float* bhh0 = (const float*)d_in[6];
  const float* Wih1 = (const float*)d_in[7];
  const float* Whh1 = (const float*)d_in[8];
  const float* bih1 = (const float*)d_in[9];
  const float* bhh1 = (const float*)d_in[10];
  const float* flow_u = (const float*)d_in[11];
  const float* flow_w = (const float*)d_in[12];
  const float* flow_b = (const float*)d_in[13];
  const float* feat_W = (const float*)d_in[14];
  const float* feat_b = (const float*)d_in[15];
  const float* ctrl_W1 = (const float*)d_in[16];
  const float* ctrl_b1 = (const float*)d_in[17];
  const float* ctrl_W2 = (const float*)d_in[18];
  const float* ctrl_b2 = (const float*)d_in[19];
  const float* cmuW = (const float*)d_in[20];
  const float* cmub = (const float*)d_in[21];
  const float* outW = (const float*)d_in[22];
  const float* outb = (const float*)d_in[23];

  char* ws = (char*)d_ws;
  size_t off = 0;
  auto alloc = [&](size_t bytes) -> char* {
    char* p = ws + off;
    off += (bytes + 255) & ~(size_t)255;
    return p;
  };
  short* covp  = (short*)alloc(49152ull * 64 * 2);
  short* labp  = (short*)alloc(32768ull * 32 * 2);
  short* Wih0p = (short*)alloc(1536ull * 64 * 2);
  short* Whh0p = (short*)alloc(1536ull * 512 * 2);
  short* Wih1p = (short*)alloc(1536ull * 512 * 2);
  short* Whh1p = (short*)alloc(1536ull * 512 * 2);
  float* bih0p = (float*)alloc(1536 * 4);
  float* bhh0p = (float*)alloc(1536 * 4);
  float* bih1p = (float*)alloc(1536 * 4);
  float* bhh1p = (float*)alloc(1536 * 4);
  short* featWb = (short*)alloc(64ull * 512 * 2);
  short* W1b   = (short*)alloc(128ull * 32 * 2);
  short* W2b   = (short*)alloc(128ull * 128 * 2);
  short* xgc   = (short*)alloc(48ull * 256 * 1536 * 2);   // chunk buffer
  short* h1buf = (short*)alloc(193ull * 256 * 512 * 2);
  short* cfbuf = (short*)alloc(193ull * 256 * 512 * 2);
  unsigned int* ctr = (unsigned int*)alloc(8 * 16 * 64 * 4);  // 8 dispatch segments
  unsigned int* flg = (unsigned int*)alloc(8 * 16 * 16 * 4);  // 8 dispatch segments
  float* feat_all = (float*)xgc;                          // overlays after scans
  short* hdnb     = (short*)((char*)xgc + 12582912);
  float* ctrlpre  = (float*)((char*)xgc + 20971520);

  hipMemsetAsync(ctr, 0, 8 * 16 * 64 * 4, stream);
  hipMemsetAsync(flg, 0, 8 * 16 * 16 * 4, stream);
  hipMemsetAsync(h1buf, 0, 256 * 512 * 2, stream);  // t=0 slot zeros
  hipMemsetAsync(cfbuf, 0, 256 * 512 * 2, stream);

  pack_cov_k<<<2048, 256, 0, stream>>>(past_input, future_input, covp);
  pack_lab_k<<<1024, 256, 0, stream>>>(past_label, labp);
  pack_gru_k<<<1024, 256, 0, stream>>>(Wih0, Whh0, bih0, bhh0, 64, Wih0p, Whh0p, bih0p, bhh0p);
  pack_gru_k<<<1024, 256, 0, stream>>>(Wih1, Whh1, bih1, bhh1, 512, Wih1p, Whh1p, bih1p, bhh1p);
  pack_misc_k<<<64, 256, 0, stream>>>(feat_W, ctrl_W1, ctrl_W2, featWb, W1b, W2b);

  // layer 0: scheme A/B across chunks (c even: counter, c odd: flags)
  for (int c = 0; c < 4; ++c) {
    gemm_bt_k<64, true, false, false><<<dim3(96, 12), 256, 0, stream>>>(
        covp + (size_t)c * 48 * 256 * 64, Wih0p, bih0p, xgc, 12288, 1536, 64);
    int d = c;
    if (c & 1)
      gru_scan_k<2><<<256, 256, 0, stream>>>(xgc, Whh0p, bhh0p, h1buf,
                                             ctr + d * 1024, flg + d * 256, c * 48);
    else
      gru_scan_k<1><<<256, 256, 0, stream>>>(xgc, Whh0p, bhh0p, h1buf,
                                             ctr + d * 1024, flg + d * 256, c * 48);
  }
  // layer 1 (AFRAG gemm reads h1buf fragment image directly)
  for (int c = 0; c < 4; ++c) {
    gemm_bt_k<64, true, false, true><<<dim3(96, 12), 256, 0, stream>>>(
        h1buf + (size_t)(1 + c * 48) * 131072, Wih1p, bih1p, xgc, 12288, 1536, 512);
    int d = 4 + c;
    if (c & 1)
      gru_scan_k<2><<<256, 256, 0, stream>>>(xgc, Whh1p, bhh1p, cfbuf,
                                             ctr + d * 1024, flg + d * 256, c * 48);
    else
      gru_scan_k<1><<<256, 256, 0, stream>>>(xgc, Whh1p, bhh1p, cfbuf,
                                             ctr + d * 1024, flg + d * 256, c * 48);
  }
  // parallel precompute for the VAE scan
  gemm_bt_k<64, false, false, true><<<dim3(384, 1), 256, 0, stream>>>(
      cfbuf + 131072, featWb, feat_b, feat_all, 49152, 64, 512);
  gemm_bt_k<32, true, true, false><<<dim3(256, 1), 256, 0, stream>>>(
      labp, W1b, ctrl_b1, hdnb, 32768, 128, 32);
  gemm_bt_k<64, false, false, false><<<dim3(256, 1), 256, 0, stream>>>(
      hdnb, W2b, ctrl_b2, ctrlpre, 32768, 128, 128);

  vae_k<<<256, 128, 0, stream>>>(feat_all, ctrlpre, flow_u, flow_w, flow_b,
                                 outW, outb, ctrl_W1, ctrl_b1, ctrl_W2, ctrl_b2,
                                 cmuW, cmub, (float*)d_out);
}